// Round 6
// baseline (718.922 us; speedup 1.0000x reference)
//
#include <hip/hip_runtime.h>
#include <cstdint>
#include <cstddef>

// ---------------- wave helpers ----------------
__device__ __forceinline__ float rl_f32(float v, int lane) {
    return __uint_as_float((unsigned)__builtin_amdgcn_readlane((int)__float_as_uint(v), lane));
}
__device__ __forceinline__ float wave_sum(float v) {
#pragma unroll
    for (int o = 32; o > 0; o >>= 1) v += __shfl_xor(v, o, 64);
    return v;
}
__device__ __forceinline__ unsigned wave_sum_u32(unsigned v) {
#pragma unroll
    for (int o = 32; o > 0; o >>= 1) v += (unsigned)__shfl_xor((int)v, o, 64);
    return v;
}
__device__ __forceinline__ float wave_max(float v) {
#pragma unroll
    for (int o = 32; o > 0; o >>= 1) v = fmaxf(v, __shfl_xor(v, o, 64));
    return v;
}

// ---------------- zero counters + marks ----------------
__global__ void zero_kernel(unsigned* __restrict__ cnt_u, unsigned char* __restrict__ mark_u, int nU,
                            unsigned* __restrict__ cnt_s, unsigned char* __restrict__ mark_s, int nS) {
    int i = blockIdx.x * blockDim.x + threadIdx.x;
    int tot = nU + nS;
    if (i >= tot) return;
    if (i < nU) { cnt_u[i] = 0u; mark_u[i] = 0; }
    else        { cnt_s[i - nU] = 0u; mark_s[i - nU] = 0; }
}

// ---------------- mark requested destinations ----------------
__global__ void mark_kernel(const int* __restrict__ uIdx, unsigned char* __restrict__ mark_u,
                            const int* __restrict__ sIdx, unsigned char* __restrict__ mark_s, int B) {
    int t = blockIdx.x * blockDim.x + threadIdx.x;
    if (t < B)          mark_u[uIdx[t]] = 1;
    else if (t < 2 * B) mark_s[sIdx[t - B]] = 1;
}

// ---------------- count in-degree (requested dsts only) ----------------
__global__ void count_kernel(const int* __restrict__ u_dst, int EU, unsigned* __restrict__ cnt_u,
                             const unsigned char* __restrict__ mark_u,
                             const int* __restrict__ s_dst, int ES, unsigned* __restrict__ cnt_s,
                             const unsigned char* __restrict__ mark_s) {
    int e = blockIdx.x * blockDim.x + threadIdx.x;
    int tot = EU + ES;
    if (e >= tot) return;
    if (e < EU) {
        int d = u_dst[e];
        if (mark_u[d]) atomicAdd(&cnt_u[d], 1u);
    } else {
        int d = s_dst[e - EU];
        if (mark_s[d]) atomicAdd(&cnt_s[d], 1u);
    }
}

// ---------------- scan phase 1: per-tile inclusive scan + tile sums ----------------
#define SCAN_TPB 256
#define SCAN_VPT 8
#define SCAN_TILE 2048

__global__ __launch_bounds__(SCAN_TPB) void scan1_kernel(
    const unsigned* __restrict__ cnt_u, unsigned* __restrict__ indptr_u, unsigned* __restrict__ sums_u, int nU, int nbU,
    const unsigned* __restrict__ cnt_s, unsigned* __restrict__ indptr_s, unsigned* __restrict__ sums_s, int nS) {
    int b = (int)blockIdx.x;
    const unsigned* cnt; unsigned* indptr; unsigned* sums; int n, tile;
    if (b < nbU) { cnt = cnt_u; indptr = indptr_u; sums = sums_u; n = nU; tile = b; }
    else         { cnt = cnt_s; indptr = indptr_s; sums = sums_s; n = nS; tile = b - nbU; }
    int base = tile * SCAN_TILE + (int)threadIdx.x * SCAN_VPT;
    unsigned v[SCAN_VPT];
#pragma unroll
    for (int j = 0; j < SCAN_VPT; ++j) { int i = base + j; v[j] = (i < n) ? cnt[i] : 0u; }
#pragma unroll
    for (int j = 1; j < SCAN_VPT; ++j) v[j] += v[j - 1];
    __shared__ unsigned sh[SCAN_TPB];
    sh[threadIdx.x] = v[SCAN_VPT - 1];
    __syncthreads();
    for (int d = 1; d < SCAN_TPB; d <<= 1) {
        unsigned t = (threadIdx.x >= (unsigned)d) ? sh[threadIdx.x - d] : 0u;
        __syncthreads();
        sh[threadIdx.x] += t;
        __syncthreads();
    }
    unsigned prefix = (threadIdx.x > 0) ? sh[threadIdx.x - 1] : 0u;
#pragma unroll
    for (int j = 0; j < SCAN_VPT; ++j) { int i = base + j; if (i < n) indptr[i + 1] = v[j] + prefix; }
    if (threadIdx.x == SCAN_TPB - 1) sums[tile] = sh[SCAN_TPB - 1];
}

// ---------------- scan phase 2+3 fused: add tile-prefix, produce fill ----------------
__global__ __launch_bounds__(SCAN_TPB) void scanf_kernel(
    const unsigned* __restrict__ cnt_u, unsigned* __restrict__ indptr_u, unsigned* __restrict__ fill_u,
    const unsigned* __restrict__ sums_u, int nU, int nbU,
    const unsigned* __restrict__ cnt_s, unsigned* __restrict__ indptr_s, unsigned* __restrict__ fill_s,
    const unsigned* __restrict__ sums_s, int nS) {
    int b = (int)blockIdx.x;
    const unsigned* cnt; unsigned* indptr; unsigned* fill; const unsigned* sums; int n, tile;
    if (b < nbU) { cnt = cnt_u; indptr = indptr_u; fill = fill_u; sums = sums_u; n = nU; tile = b; }
    else         { cnt = cnt_s; indptr = indptr_s; fill = fill_s; sums = sums_s; n = nS; tile = b - nbU; }
    // exclusive prefix of tile sums, computed wave-parallel (nb <= 128)
    int lane = threadIdx.x & 63;
    unsigned a0 = (lane < tile) ? sums[lane] : 0u;
    unsigned a1 = (lane + 64 < tile) ? sums[lane + 64] : 0u;
    unsigned off = wave_sum_u32(a0 + a1);
    int base = tile * SCAN_TILE + (int)threadIdx.x * SCAN_VPT;
#pragma unroll
    for (int j = 0; j < SCAN_VPT; ++j) {
        int i = base + j;
        if (i < n) {
            unsigned incl = indptr[i + 1] + off;
            indptr[i + 1] = incl;
            fill[i] = incl - cnt[i];
        }
    }
    if (b == 0 && threadIdx.x == 0) { indptr_u[0] = 0u; indptr_s[0] = 0u; }
}

// ---------------- scatter edges into CSR (requested dsts only) ----------------
__global__ void scatter_kernel(const int* __restrict__ u_src, const int* __restrict__ u_dst, int EU,
                               unsigned* __restrict__ fill_u, unsigned* __restrict__ csr_u,
                               const unsigned char* __restrict__ mark_u,
                               const int* __restrict__ s_src, const int* __restrict__ s_dst, int ES,
                               unsigned* __restrict__ fill_s, unsigned* __restrict__ csr_s,
                               const unsigned char* __restrict__ mark_s) {
    int e = blockIdx.x * blockDim.x + threadIdx.x;
    int tot = EU + ES;
    if (e >= tot) return;
    if (e < EU) {
        int d = u_dst[e];
        if (mark_u[d]) {
            unsigned pos = atomicAdd(&fill_u[d], 1u);
            csr_u[pos] = (unsigned)u_src[e];
        }
    } else {
        int ee = e - EU;
        int d = s_dst[ee];
        if (mark_s[d]) {
            unsigned pos = atomicAdd(&fill_s[d], 1u);
            csr_s[pos] = (unsigned)s_src[ee];
        }
    }
}

// ---------------- el/er for all nodes (wq computed in-block in LDS) ----------------
__global__ __launch_bounds__(256) void eler_kernel(
    const float* __restrict__ u_W, const float* __restrict__ u_al, const float* __restrict__ u_ar,
    const float* __restrict__ s_W, const float* __restrict__ s_al, const float* __restrict__ s_ar,
    const float* __restrict__ user_emb, float4* __restrict__ elr_u, int nU,
    const float* __restrict__ serv_emb, float4* __restrict__ elr_s, int nS) {
    __shared__ float4 wq[128]; // [0..64) user, [64..128) serv
    int t = threadIdx.x;
    if (t < 128) {
        const float* W  = (t < 64) ? u_W : s_W;
        const float* al = (t < 64) ? u_al : s_al;
        const float* ar = (t < 64) ? u_ar : s_ar;
        int k = t & 63;
        float a0 = 0.f, a1 = 0.f, a2 = 0.f, a3 = 0.f;
        for (int d = 0; d < 64; ++d) {
            float w0 = W[k * 128 + d], w1 = W[k * 128 + 64 + d];
            a0 += w0 * al[d];      a1 += w1 * al[64 + d];
            a2 += w0 * ar[d];      a3 += w1 * ar[64 + d];
        }
        wq[t] = make_float4(a0, a1, a2, a3);
    }
    __syncthreads();
    int n = blockIdx.x * 256 + t;
    int tot = nU + nS;
    if (n >= tot) return;
    const float* feat; const float4* wqp; float4* elr; int i;
    if (n < nU) { i = n;      feat = user_emb + (size_t)i * 64; wqp = wq;      elr = elr_u; }
    else        { i = n - nU; feat = serv_emb + (size_t)i * 64; wqp = wq + 64; elr = elr_s; }
    float a0 = 0.f, a1 = 0.f, a2 = 0.f, a3 = 0.f;
    const float4* f4 = (const float4*)feat;
#pragma unroll
    for (int q = 0; q < 16; ++q) {
        float4 f = f4[q];
        float4 w;
        w = wqp[q * 4 + 0]; a0 = fmaf(f.x, w.x, a0); a1 = fmaf(f.x, w.y, a1); a2 = fmaf(f.x, w.z, a2); a3 = fmaf(f.x, w.w, a3);
        w = wqp[q * 4 + 1]; a0 = fmaf(f.y, w.x, a0); a1 = fmaf(f.y, w.y, a1); a2 = fmaf(f.y, w.z, a2); a3 = fmaf(f.y, w.w, a3);
        w = wqp[q * 4 + 2]; a0 = fmaf(f.z, w.x, a0); a1 = fmaf(f.z, w.y, a1); a2 = fmaf(f.z, w.z, a2); a3 = fmaf(f.z, w.w, a3);
        w = wqp[q * 4 + 3]; a0 = fmaf(f.w, w.x, a0); a1 = fmaf(f.w, w.y, a1); a2 = fmaf(f.w, w.z, a2); a3 = fmaf(f.w, w.w, a3);
    }
    elr[i] = make_float4(a0, a1, a2, a3);
}

// ---------------- gather: attention softmax + alpha-weighted feature aggregation ----------------
// One wave per requested destination. No LDS; launch_bounds(256,4) so no spill.
__global__ __launch_bounds__(256, 4) void gather_kernel(
    const int* __restrict__ uIdx, const unsigned* __restrict__ indptr_u, const unsigned* __restrict__ csr_u,
    const float* __restrict__ elr_u, const float* __restrict__ user_emb,
    const int* __restrict__ sIdx, const unsigned* __restrict__ indptr_s, const unsigned* __restrict__ csr_s,
    const float* __restrict__ elr_s, const float* __restrict__ serv_emb,
    float* __restrict__ aggbuf, int B, int nBlocksU) {
    bool isU = (int)blockIdx.x < nBlocksU;
    const int* idx; const unsigned* indptr; const unsigned* csr; const float* elr; const float* emb;
    int bb4 = isU ? (int)blockIdx.x : (int)blockIdx.x - nBlocksU;
    if (isU) { idx = uIdx; indptr = indptr_u; csr = csr_u; elr = elr_u; emb = user_emb; }
    else     { idx = sIdx; indptr = indptr_s; csr = csr_s; elr = elr_s; emb = serv_emb; }
    int wid = threadIdx.x >> 6, lane = threadIdx.x & 63;
    int b = bb4 * 4 + wid;
    if (b >= B) return;
    int row = isU ? b : B + b;
    const float2* elr2 = (const float2*)elr;

    int d = idx[b];
    unsigned s = indptr[d];
    int deg = (int)(indptr[d + 1] - s);
    float2 erp = elr2[(size_t)d * 2 + 1];
    float er0 = erp.x, er1 = erp.y;

    float agg0 = 0.f, agg1 = 0.f;
    if (deg <= 64) {
        unsigned mysrc = 0;
        if (lane < deg) mysrc = csr[s + lane];
        float2 elp = elr2[(size_t)mysrc * 2];
        float e0 = elp.x + er0; e0 = e0 > 0.f ? e0 : 0.2f * e0;
        float e1 = elp.y + er1; e1 = e1 > 0.f ? e1 : 0.2f * e1;
        if (lane >= deg) { e0 = -1e30f; e1 = -1e30f; }
        float m0 = wave_max(e0), m1 = wave_max(e1);
        float p0 = (lane < deg) ? expf(e0 - m0) : 0.f;
        float p1 = (lane < deg) ? expf(e1 - m1) : 0.f;
        float sum0 = wave_sum(p0), sum1 = wave_sum(p1);
        float alpha0 = p0 * (1.0f / sum0);
        float alpha1 = p1 * (1.0f / sum1);

        for (int cb = 0; cb < deg; cb += 16) {
            float f[16];
#pragma unroll
            for (int jj = 0; jj < 16; ++jj) {
                int j2 = cb + jj;
                if (j2 < deg) {
                    unsigned sj = (unsigned)__builtin_amdgcn_readlane((int)mysrc, j2);
                    f[jj] = emb[(size_t)sj * 64 + lane];
                } else f[jj] = 0.f;
            }
#pragma unroll
            for (int jj = 0; jj < 16; ++jj) {
                int j2 = cb + jj;
                if (j2 < deg) {
                    agg0 = fmaf(rl_f32(alpha0, j2), f[jj], agg0);
                    agg1 = fmaf(rl_f32(alpha1, j2), f[jj], agg1);
                }
            }
        }
    } else {
        // slow path (deg > 64): 3-pass strided
        float m0 = -1e30f, m1 = -1e30f;
        for (int j = lane; j < deg; j += 64) {
            int src = (int)csr[s + j];
            float2 elp = elr2[(size_t)src * 2];
            float e0 = elp.x + er0; e0 = e0 > 0.f ? e0 : 0.2f * e0;
            float e1 = elp.y + er1; e1 = e1 > 0.f ? e1 : 0.2f * e1;
            m0 = fmaxf(m0, e0); m1 = fmaxf(m1, e1);
        }
        m0 = wave_max(m0); m1 = wave_max(m1);
        float s0 = 0.f, s1 = 0.f;
        for (int j = lane; j < deg; j += 64) {
            int src = (int)csr[s + j];
            float2 elp = elr2[(size_t)src * 2];
            float e0 = elp.x + er0; e0 = e0 > 0.f ? e0 : 0.2f * e0;
            float e1 = elp.y + er1; e1 = e1 > 0.f ? e1 : 0.2f * e1;
            s0 += expf(e0 - m0); s1 += expf(e1 - m1);
        }
        s0 = wave_sum(s0); s1 = wave_sum(s1);
        float r0 = 1.0f / s0, r1 = 1.0f / s1;
        for (int j = 0; j < deg; ++j) {
            int src = (int)csr[s + j];
            float2 elp = elr2[(size_t)src * 2];
            float e0 = elp.x + er0; e0 = e0 > 0.f ? e0 : 0.2f * e0;
            float e1 = elp.y + er1; e1 = e1 > 0.f ? e1 : 0.2f * e1;
            float a0 = expf(e0 - m0) * r0;
            float a1 = expf(e1 - m1) * r1;
            float f = emb[(size_t)src * 64 + lane];
            agg0 = fmaf(a0, f, agg0); agg1 = fmaf(a1, f, agg1);
        }
    }

    aggbuf[(size_t)row * 128 + lane] = agg0;
    aggbuf[(size_t)row * 128 + 64 + lane] = agg1;
}

// ---------------- proj: agg @ W + bias, LN, ELU, head-mean, +emb -> xbuf ----------------
// 512 threads (8 waves) share one 32KB W tile; 2-way split acc chains.
#define PROJ_BLOCKS 512 // per graph
__global__ __launch_bounds__(512, 4) void proj_kernel(
    const int* __restrict__ uIdx, const float* __restrict__ u_W, const float* __restrict__ u_bias,
    const float* __restrict__ u_g, const float* __restrict__ u_b, const float* __restrict__ user_emb,
    const int* __restrict__ sIdx, const float* __restrict__ s_W, const float* __restrict__ s_bias,
    const float* __restrict__ s_g, const float* __restrict__ s_b, const float* __restrict__ serv_emb,
    const float* __restrict__ aggbuf, float* __restrict__ xbuf, int B) {
    __shared__ float2 Wp[64 * 64]; // 32KB: Wp[k*64+l] = (W[k][l], W[k][64+l])
    bool isU = (int)blockIdx.x < PROJ_BLOCKS;
    const int* idx; const float* W; const float* bias; const float* g; const float* bb; const float* emb;
    int bbase;
    if (isU) { idx = uIdx; W = u_W; bias = u_bias; g = u_g; bb = u_b; emb = user_emb; bbase = (int)blockIdx.x; }
    else     { idx = sIdx; W = s_W; bias = s_bias; g = s_g; bb = s_b; emb = serv_emb; bbase = (int)blockIdx.x - PROJ_BLOCKS; }
    for (int t = threadIdx.x; t < 4096; t += 512) {
        int k = t >> 6, l = t & 63;
        Wp[t] = make_float2(W[k * 128 + l], W[k * 128 + 64 + l]);
    }
    __syncthreads();

    int wid = threadIdx.x >> 6, lane = threadIdx.x & 63;
    int xoff = isU ? 0 : 64;
    int rowoff = isU ? 0 : B;
    float biasa = bias[lane], biasb = bias[64 + lane];
    float ga = g[lane], gb2 = g[64 + lane];
    float ba = bb[lane], bb2 = bb[64 + lane];

    for (int b = bbase * 8 + wid; b < B; b += PROJ_BLOCKS * 8) {
        int d = idx[b];
        float embv = emb[(size_t)d * 64 + lane];              // prefetch (random row)
        int row = rowoff + b;
        float agg0 = aggbuf[(size_t)row * 128 + lane];
        float agg1 = aggbuf[(size_t)row * 128 + 64 + lane];

        float acc0a = 0.f, acc1a = 0.f, acc0b = 0.f, acc1b = 0.f;
#pragma unroll
        for (int k = 0; k < 64; k += 2) {
            float a0 = rl_f32(agg0, k);
            float a1 = rl_f32(agg1, k);
            float a0b = rl_f32(agg0, k + 1);
            float a1b = rl_f32(agg1, k + 1);
            float2 wa = Wp[k * 64 + lane];
            float2 wb = Wp[(k + 1) * 64 + lane];
            acc0a = fmaf(a0, wa.x, acc0a);  acc1a = fmaf(a1, wa.y, acc1a);
            acc0b = fmaf(a0b, wb.x, acc0b); acc1b = fmaf(a1b, wb.y, acc1b);
        }
        float acc0 = acc0a + acc0b, acc1 = acc1a + acc1b;

        float o0 = acc0 + biasa, o1 = acc1 + biasb;
        float tot = wave_sum(o0 + o1);
        float mu = tot * (1.0f / 128.0f);
        float d0 = o0 - mu, d1 = o1 - mu;
        float var = wave_sum(d0 * d0 + d1 * d1) * (1.0f / 128.0f);
        float rstd = rsqrtf(var + 1e-5f);
        float l0 = d0 * rstd * ga + ba;
        float l1 = d1 * rstd * gb2 + bb2;
        l0 = l0 > 0.f ? l0 : expm1f(l0);
        l1 = l1 > 0.f ? l1 : expm1f(l1);
        float v = 0.5f * (l0 + l1) + embv;
        xbuf[(size_t)b * 128 + xoff + lane] = v;
    }
}

// ---------------- MLP layer 1: out = relu(LN(in @ W + b)) ----------------
// 1024 threads (16 waves) share one 64KB W tile; 4-way split acc chains.
#define MLP_BLOCKS 256
__global__ __launch_bounds__(1024, 4) void mlp_kernel(const float* __restrict__ xin, float* __restrict__ xout,
                                                      const float* __restrict__ W, const float* __restrict__ bvec,
                                                      const float* __restrict__ g, const float* __restrict__ bb,
                                                      int B) {
    __shared__ float2 Wp[128 * 64]; // 64KB
    for (int t = threadIdx.x; t < 8192; t += 1024) {
        int k = t >> 6, l = t & 63;
        Wp[t] = make_float2(W[k * 128 + l], W[k * 128 + 64 + l]);
    }
    __syncthreads();
    int wid = threadIdx.x >> 6, lane = threadIdx.x & 63;
    for (int r = (int)blockIdx.x * 16 + wid; r < B; r += MLP_BLOCKS * 16) {
        float x0 = xin[(size_t)r * 128 + lane];
        float x1 = xin[(size_t)r * 128 + 64 + lane];
        float acc0a = 0.f, acc1a = 0.f, acc0b = 0.f, acc1b = 0.f;
#pragma unroll
        for (int k = 0; k < 128; k += 2) {
            float xa = rl_f32((k < 64) ? x0 : x1, k & 63);
            float xb = rl_f32(((k + 1) < 64) ? x0 : x1, (k + 1) & 63);
            float2 wa = Wp[k * 64 + lane];
            float2 wb = Wp[(k + 1) * 64 + lane];
            acc0a = fmaf(xa, wa.x, acc0a); acc1a = fmaf(xa, wa.y, acc1a);
            acc0b = fmaf(xb, wb.x, acc0b); acc1b = fmaf(xb, wb.y, acc1b);
        }
        float o0 = acc0a + acc0b + bvec[lane], o1 = acc1a + acc1b + bvec[64 + lane];
        float tot = wave_sum(o0 + o1);
        float mu = tot * (1.0f / 128.0f);
        float d0 = o0 - mu, d1 = o1 - mu;
        float var = wave_sum(d0 * d0 + d1 * d1) * (1.0f / 128.0f);
        float rstd = rsqrtf(var + 1e-5f);
        float l0 = d0 * rstd * g[lane] + bb[lane];
        float l1 = d1 * rstd * g[64 + lane] + bb[64 + lane];
        l0 = fmaxf(l0, 0.f); l1 = fmaxf(l1, 0.f);
        xout[(size_t)r * 128 + lane] = l0;
        xout[(size_t)r * 128 + 64 + lane] = l1;
    }
}

// ---------------- MLP layer 2 fused with final dot + sigmoid ----------------
__global__ __launch_bounds__(1024, 4) void mlpfin_kernel(const float* __restrict__ xin, float* __restrict__ out,
                                                         const float* __restrict__ W, const float* __restrict__ bvec,
                                                         const float* __restrict__ g, const float* __restrict__ bb,
                                                         const float* __restrict__ W3, const float* __restrict__ b3,
                                                         int B) {
    __shared__ float2 Wp[128 * 64]; // 64KB
    for (int t = threadIdx.x; t < 8192; t += 1024) {
        int k = t >> 6, l = t & 63;
        Wp[t] = make_float2(W[k * 128 + l], W[k * 128 + 64 + l]);
    }
    __syncthreads();
    int wid = threadIdx.x >> 6, lane = threadIdx.x & 63;
    float w3a = W3[lane], w3b = W3[64 + lane];
    float b3v = b3[0];
    for (int r = (int)blockIdx.x * 16 + wid; r < B; r += MLP_BLOCKS * 16) {
        float x0 = xin[(size_t)r * 128 + lane];
        float x1 = xin[(size_t)r * 128 + 64 + lane];
        float acc0a = 0.f, acc1a = 0.f, acc0b = 0.f, acc1b = 0.f;
#pragma unroll
        for (int k = 0; k < 128; k += 2) {
            float xa = rl_f32((k < 64) ? x0 : x1, k & 63);
            float xb = rl_f32(((k + 1) < 64) ? x0 : x1, (k + 1) & 63);
            float2 wa = Wp[k * 64 + lane];
            float2 wb = Wp[(k + 1) * 64 + lane];
            acc0a = fmaf(xa, wa.x, acc0a); acc1a = fmaf(xa, wa.y, acc1a);
            acc0b = fmaf(xb, wb.x, acc0b); acc1b = fmaf(xb, wb.y, acc1b);
        }
        float o0 = acc0a + acc0b + bvec[lane], o1 = acc1a + acc1b + bvec[64 + lane];
        float tot = wave_sum(o0 + o1);
        float mu = tot * (1.0f / 128.0f);
        float d0 = o0 - mu, d1 = o1 - mu;
        float var = wave_sum(d0 * d0 + d1 * d1) * (1.0f / 128.0f);
        float rstd = rsqrtf(var + 1e-5f);
        float l0 = d0 * rstd * g[lane] + bb[lane];
        float l1 = d1 * rstd * g[64 + lane] + bb[64 + lane];
        l0 = fmaxf(l0, 0.f); l1 = fmaxf(l1, 0.f);
        float acc = wave_sum(fmaf(l0, w3a, l1 * w3b)) + b3v;
        if (lane == 0) out[r] = 1.0f / (1.0f + expf(-acc));
    }
}

// ---------------- host launcher ----------------
extern "C" void kernel_launch(void* const* d_in, const int* in_sizes, int n_in,
                              void* d_out, int out_size, void* d_ws, size_t ws_size,
                              hipStream_t stream) {
    const int*   userIdx  = (const int*)d_in[0];
    const int*   servIdx  = (const int*)d_in[1];
    const int*   u_src    = (const int*)d_in[2];
    const int*   u_dst    = (const int*)d_in[3];
    const int*   s_src    = (const int*)d_in[4];
    const int*   s_dst    = (const int*)d_in[5];
    const float* user_emb = (const float*)d_in[6];
    const float* serv_emb = (const float*)d_in[7];
    const float* u_W      = (const float*)d_in[8];
    const float* u_al     = (const float*)d_in[9];
    const float* u_ar     = (const float*)d_in[10];
    const float* u_bias   = (const float*)d_in[11];
    const float* u_ln_g   = (const float*)d_in[12];
    const float* u_ln_b   = (const float*)d_in[13];
    const float* s_W      = (const float*)d_in[14];
    const float* s_al     = (const float*)d_in[15];
    const float* s_ar     = (const float*)d_in[16];
    const float* s_bias   = (const float*)d_in[17];
    const float* s_ln_g   = (const float*)d_in[18];
    const float* s_ln_b   = (const float*)d_in[19];
    const float* W1       = (const float*)d_in[20];
    const float* b1       = (const float*)d_in[21];
    const float* ln1_g    = (const float*)d_in[22];
    const float* ln1_b    = (const float*)d_in[23];
    const float* W2       = (const float*)d_in[24];
    const float* b2       = (const float*)d_in[25];
    const float* ln2_g    = (const float*)d_in[26];
    const float* ln2_b    = (const float*)d_in[27];
    const float* W3       = (const float*)d_in[28];
    const float* b3       = (const float*)d_in[29];

    const int B  = in_sizes[0];
    const int EU = in_sizes[2];
    const int ES = in_sizes[4];
    const int NU = in_sizes[6] / 64;
    const int NS = in_sizes[7] / 64;

    // workspace carve-up (256B aligned)
    char* w = (char*)d_ws;
    size_t off = 0;
    auto alloc = [&](size_t bytes) -> void* {
        void* p = w + off;
        off = (off + bytes + 255) & ~(size_t)255;
        return p;
    };
    unsigned* cnt_u    = (unsigned*)alloc((size_t)NU * 4);
    unsigned char* mark_u = (unsigned char*)alloc((size_t)NU);
    unsigned* indptr_u = (unsigned*)alloc((size_t)(NU + 1) * 4);
    unsigned* fill_u   = (unsigned*)alloc((size_t)NU * 4);
    unsigned* csr_u    = (unsigned*)alloc((size_t)EU * 4);
    unsigned* cnt_s    = (unsigned*)alloc((size_t)NS * 4);
    unsigned char* mark_s = (unsigned char*)alloc((size_t)NS);
    unsigned* indptr_s = (unsigned*)alloc((size_t)(NS + 1) * 4);
    unsigned* fill_s   = (unsigned*)alloc((size_t)NS * 4);
    unsigned* csr_s    = (unsigned*)alloc((size_t)ES * 4);
    unsigned* sums_u   = (unsigned*)alloc(256 * 4);
    unsigned* sums_s   = (unsigned*)alloc(256 * 4);
    float*    elr_u    = (float*)   alloc((size_t)NU * 4 * sizeof(float));
    float*    elr_s    = (float*)   alloc((size_t)NS * 4 * sizeof(float));
    float*    aggbuf   = (float*)   alloc((size_t)2 * B * 128 * sizeof(float));
    float*    xbuf     = (float*)   alloc((size_t)B * 128 * sizeof(float));
    float*    ybuf     = aggbuf;  // aggbuf is dead after proj; reuse for MLP intermediate
    (void)ws_size;

    const int nbU = (NU + SCAN_TILE - 1) / SCAN_TILE;
    const int nbS = (NS + SCAN_TILE - 1) / SCAN_TILE;
    const int totN = NU + NS;
    const int totE = EU + ES;

    zero_kernel<<<(totN + 255) / 256, 256, 0, stream>>>(cnt_u, mark_u, NU, cnt_s, mark_s, NS);
    mark_kernel<<<(2 * B + 255) / 256, 256, 0, stream>>>(userIdx, mark_u, servIdx, mark_s, B);
    count_kernel<<<(totE + 255) / 256, 256, 0, stream>>>(u_dst, EU, cnt_u, mark_u,
                                                         s_dst, ES, cnt_s, mark_s);
    scan1_kernel<<<nbU + nbS, SCAN_TPB, 0, stream>>>(cnt_u, indptr_u, sums_u, NU, nbU,
                                                     cnt_s, indptr_s, sums_s, NS);
    scanf_kernel<<<nbU + nbS, SCAN_TPB, 0, stream>>>(cnt_u, indptr_u, fill_u, sums_u, NU, nbU,
                                                     cnt_s, indptr_s, fill_s, sums_s, NS);
    scatter_kernel<<<(totE + 255) / 256, 256, 0, stream>>>(u_src, u_dst, EU, fill_u, csr_u, mark_u,
                                                           s_src, s_dst, ES, fill_s, csr_s, mark_s);
    eler_kernel<<<(totN + 255) / 256, 256, 0, stream>>>(u_W, u_al, u_ar, s_W, s_al, s_ar,
                                                        user_emb, (float4*)elr_u, NU,
                                                        serv_emb, (float4*)elr_s, NS);
    const int nBlocksU = (B + 3) / 4;
    gather_kernel<<<2 * nBlocksU, 256, 0, stream>>>(
        userIdx, indptr_u, csr_u, elr_u, user_emb,
        servIdx, indptr_s, csr_s, elr_s, serv_emb,
        aggbuf, B, nBlocksU);
    proj_kernel<<<2 * PROJ_BLOCKS, 512, 0, stream>>>(
        userIdx, u_W, u_bias, u_ln_g, u_ln_b, user_emb,
        servIdx, s_W, s_bias, s_ln_g, s_ln_b, serv_emb,
        aggbuf, xbuf, B);
    mlp_kernel<<<MLP_BLOCKS, 1024, 0, stream>>>(xbuf, ybuf, W1, b1, ln1_g, ln1_b, B);
    mlpfin_kernel<<<MLP_BLOCKS, 1024, 0, stream>>>(ybuf, (float*)d_out, W2, b2, ln2_g, ln2_b, W3, b3, B);
}

// Round 7
// 419.227 us; speedup vs baseline: 1.7149x; 1.7149x over previous
//
#include <hip/hip_runtime.h>
#include <cstdint>
#include <cstddef>

// ---------------- wave helpers ----------------
__device__ __forceinline__ float rl_f32(float v, int lane) {
    return __uint_as_float((unsigned)__builtin_amdgcn_readlane((int)__float_as_uint(v), lane));
}
__device__ __forceinline__ float wave_sum(float v) {
#pragma unroll
    for (int o = 32; o > 0; o >>= 1) v += __shfl_xor(v, o, 64);
    return v;
}
__device__ __forceinline__ unsigned wave_sum_u32(unsigned v) {
#pragma unroll
    for (int o = 32; o > 0; o >>= 1) v += (unsigned)__shfl_xor((int)v, o, 64);
    return v;
}
__device__ __forceinline__ float wave_max(float v) {
#pragma unroll
    for (int o = 32; o > 0; o >>= 1) v = fmaxf(v, __shfl_xor(v, o, 64));
    return v;
}

// ---------------- zero counters + marks ----------------
__global__ void zero_kernel(unsigned* __restrict__ cnt_u, unsigned char* __restrict__ mark_u, int nU,
                            unsigned* __restrict__ cnt_s, unsigned char* __restrict__ mark_s, int nS) {
    int i = blockIdx.x * blockDim.x + threadIdx.x;
    int tot = nU + nS;
    if (i >= tot) return;
    if (i < nU) { cnt_u[i] = 0u; mark_u[i] = 0; }
    else        { cnt_s[i - nU] = 0u; mark_s[i - nU] = 0; }
}

// ---------------- mark requested destinations ----------------
__global__ void mark_kernel(const int* __restrict__ uIdx, unsigned char* __restrict__ mark_u,
                            const int* __restrict__ sIdx, unsigned char* __restrict__ mark_s, int B) {
    int t = blockIdx.x * blockDim.x + threadIdx.x;
    if (t < B)          mark_u[uIdx[t]] = 1;
    else if (t < 2 * B) mark_s[sIdx[t - B]] = 1;
}

// ---------------- count in-degree (requested dsts only) ----------------
__global__ void count_kernel(const int* __restrict__ u_dst, int EU, unsigned* __restrict__ cnt_u,
                             const unsigned char* __restrict__ mark_u,
                             const int* __restrict__ s_dst, int ES, unsigned* __restrict__ cnt_s,
                             const unsigned char* __restrict__ mark_s) {
    int e = blockIdx.x * blockDim.x + threadIdx.x;
    int tot = EU + ES;
    if (e >= tot) return;
    if (e < EU) {
        int d = u_dst[e];
        if (mark_u[d]) atomicAdd(&cnt_u[d], 1u);
    } else {
        int d = s_dst[e - EU];
        if (mark_s[d]) atomicAdd(&cnt_s[d], 1u);
    }
}

// ---------------- scan phase 1: per-tile inclusive scan + tile sums ----------------
#define SCAN_TPB 256
#define SCAN_VPT 8
#define SCAN_TILE 2048

__global__ __launch_bounds__(SCAN_TPB) void scan1_kernel(
    const unsigned* __restrict__ cnt_u, unsigned* __restrict__ indptr_u, unsigned* __restrict__ sums_u, int nU, int nbU,
    const unsigned* __restrict__ cnt_s, unsigned* __restrict__ indptr_s, unsigned* __restrict__ sums_s, int nS) {
    int b = (int)blockIdx.x;
    const unsigned* cnt; unsigned* indptr; unsigned* sums; int n, tile;
    if (b < nbU) { cnt = cnt_u; indptr = indptr_u; sums = sums_u; n = nU; tile = b; }
    else         { cnt = cnt_s; indptr = indptr_s; sums = sums_s; n = nS; tile = b - nbU; }
    int base = tile * SCAN_TILE + (int)threadIdx.x * SCAN_VPT;
    unsigned v[SCAN_VPT];
#pragma unroll
    for (int j = 0; j < SCAN_VPT; ++j) { int i = base + j; v[j] = (i < n) ? cnt[i] : 0u; }
#pragma unroll
    for (int j = 1; j < SCAN_VPT; ++j) v[j] += v[j - 1];
    __shared__ unsigned sh[SCAN_TPB];
    sh[threadIdx.x] = v[SCAN_VPT - 1];
    __syncthreads();
    for (int d = 1; d < SCAN_TPB; d <<= 1) {
        unsigned t = (threadIdx.x >= (unsigned)d) ? sh[threadIdx.x - d] : 0u;
        __syncthreads();
        sh[threadIdx.x] += t;
        __syncthreads();
    }
    unsigned prefix = (threadIdx.x > 0) ? sh[threadIdx.x - 1] : 0u;
#pragma unroll
    for (int j = 0; j < SCAN_VPT; ++j) { int i = base + j; if (i < n) indptr[i + 1] = v[j] + prefix; }
    if (threadIdx.x == SCAN_TPB - 1) sums[tile] = sh[SCAN_TPB - 1];
}

// ---------------- scan phase 2+3 fused: add tile-prefix, produce fill ----------------
__global__ __launch_bounds__(SCAN_TPB) void scanf_kernel(
    const unsigned* __restrict__ cnt_u, unsigned* __restrict__ indptr_u, unsigned* __restrict__ fill_u,
    const unsigned* __restrict__ sums_u, int nU, int nbU,
    const unsigned* __restrict__ cnt_s, unsigned* __restrict__ indptr_s, unsigned* __restrict__ fill_s,
    const unsigned* __restrict__ sums_s, int nS) {
    int b = (int)blockIdx.x;
    const unsigned* cnt; unsigned* indptr; unsigned* fill; const unsigned* sums; int n, tile;
    if (b < nbU) { cnt = cnt_u; indptr = indptr_u; fill = fill_u; sums = sums_u; n = nU; tile = b; }
    else         { cnt = cnt_s; indptr = indptr_s; fill = fill_s; sums = sums_s; n = nS; tile = b - nbU; }
    // exclusive prefix of tile sums, computed wave-parallel (nb <= 128)
    int lane = threadIdx.x & 63;
    unsigned a0 = (lane < tile) ? sums[lane] : 0u;
    unsigned a1 = (lane + 64 < tile) ? sums[lane + 64] : 0u;
    unsigned off = wave_sum_u32(a0 + a1);
    int base = tile * SCAN_TILE + (int)threadIdx.x * SCAN_VPT;
#pragma unroll
    for (int j = 0; j < SCAN_VPT; ++j) {
        int i = base + j;
        if (i < n) {
            unsigned incl = indptr[i + 1] + off;
            indptr[i + 1] = incl;
            fill[i] = incl - cnt[i];
        }
    }
    if (b == 0 && threadIdx.x == 0) { indptr_u[0] = 0u; indptr_s[0] = 0u; }
}

// ---------------- scatter edges into CSR (requested dsts only) ----------------
__global__ void scatter_kernel(const int* __restrict__ u_src, const int* __restrict__ u_dst, int EU,
                               unsigned* __restrict__ fill_u, unsigned* __restrict__ csr_u,
                               const unsigned char* __restrict__ mark_u,
                               const int* __restrict__ s_src, const int* __restrict__ s_dst, int ES,
                               unsigned* __restrict__ fill_s, unsigned* __restrict__ csr_s,
                               const unsigned char* __restrict__ mark_s) {
    int e = blockIdx.x * blockDim.x + threadIdx.x;
    int tot = EU + ES;
    if (e >= tot) return;
    if (e < EU) {
        int d = u_dst[e];
        if (mark_u[d]) {
            unsigned pos = atomicAdd(&fill_u[d], 1u);
            csr_u[pos] = (unsigned)u_src[e];
        }
    } else {
        int ee = e - EU;
        int d = s_dst[ee];
        if (mark_s[d]) {
            unsigned pos = atomicAdd(&fill_s[d], 1u);
            csr_s[pos] = (unsigned)s_src[ee];
        }
    }
}

// ---------------- el/er for all nodes (wq computed in-block in LDS) ----------------
__global__ __launch_bounds__(256) void eler_kernel(
    const float* __restrict__ u_W, const float* __restrict__ u_al, const float* __restrict__ u_ar,
    const float* __restrict__ s_W, const float* __restrict__ s_al, const float* __restrict__ s_ar,
    const float* __restrict__ user_emb, float4* __restrict__ elr_u, int nU,
    const float* __restrict__ serv_emb, float4* __restrict__ elr_s, int nS) {
    __shared__ float4 wq[128]; // [0..64) user, [64..128) serv
    int t = threadIdx.x;
    if (t < 128) {
        const float* W  = (t < 64) ? u_W : s_W;
        const float* al = (t < 64) ? u_al : s_al;
        const float* ar = (t < 64) ? u_ar : s_ar;
        int k = t & 63;
        float a0 = 0.f, a1 = 0.f, a2 = 0.f, a3 = 0.f;
        for (int d = 0; d < 64; ++d) {
            float w0 = W[k * 128 + d], w1 = W[k * 128 + 64 + d];
            a0 += w0 * al[d];      a1 += w1 * al[64 + d];
            a2 += w0 * ar[d];      a3 += w1 * ar[64 + d];
        }
        wq[t] = make_float4(a0, a1, a2, a3);
    }
    __syncthreads();
    int n = blockIdx.x * 256 + t;
    int tot = nU + nS;
    if (n >= tot) return;
    const float* feat; const float4* wqp; float4* elr; int i;
    if (n < nU) { i = n;      feat = user_emb + (size_t)i * 64; wqp = wq;      elr = elr_u; }
    else        { i = n - nU; feat = serv_emb + (size_t)i * 64; wqp = wq + 64; elr = elr_s; }
    float a0 = 0.f, a1 = 0.f, a2 = 0.f, a3 = 0.f;
    const float4* f4 = (const float4*)feat;
#pragma unroll
    for (int q = 0; q < 16; ++q) {
        float4 f = f4[q];
        float4 w;
        w = wqp[q * 4 + 0]; a0 = fmaf(f.x, w.x, a0); a1 = fmaf(f.x, w.y, a1); a2 = fmaf(f.x, w.z, a2); a3 = fmaf(f.x, w.w, a3);
        w = wqp[q * 4 + 1]; a0 = fmaf(f.y, w.x, a0); a1 = fmaf(f.y, w.y, a1); a2 = fmaf(f.y, w.z, a2); a3 = fmaf(f.y, w.w, a3);
        w = wqp[q * 4 + 2]; a0 = fmaf(f.z, w.x, a0); a1 = fmaf(f.z, w.y, a1); a2 = fmaf(f.z, w.z, a2); a3 = fmaf(f.z, w.w, a3);
        w = wqp[q * 4 + 3]; a0 = fmaf(f.w, w.x, a0); a1 = fmaf(f.w, w.y, a1); a2 = fmaf(f.w, w.z, a2); a3 = fmaf(f.w, w.w, a3);
    }
    elr[i] = make_float4(a0, a1, a2, a3);
}

// ---------------- gather: attention softmax + alpha-weighted feature aggregation ----------------
// One wave per requested destination. No LDS.
__global__ __launch_bounds__(256, 4) void gather_kernel(
    const int* __restrict__ uIdx, const unsigned* __restrict__ indptr_u, const unsigned* __restrict__ csr_u,
    const float* __restrict__ elr_u, const float* __restrict__ user_emb,
    const int* __restrict__ sIdx, const unsigned* __restrict__ indptr_s, const unsigned* __restrict__ csr_s,
    const float* __restrict__ elr_s, const float* __restrict__ serv_emb,
    float* __restrict__ aggbuf, int B, int nBlocksU) {
    bool isU = (int)blockIdx.x < nBlocksU;
    const int* idx; const unsigned* indptr; const unsigned* csr; const float* elr; const float* emb;
    int bb4 = isU ? (int)blockIdx.x : (int)blockIdx.x - nBlocksU;
    if (isU) { idx = uIdx; indptr = indptr_u; csr = csr_u; elr = elr_u; emb = user_emb; }
    else     { idx = sIdx; indptr = indptr_s; csr = csr_s; elr = elr_s; emb = serv_emb; }
    int wid = threadIdx.x >> 6, lane = threadIdx.x & 63;
    int b = bb4 * 4 + wid;
    if (b >= B) return;
    int row = isU ? b : B + b;
    const float2* elr2 = (const float2*)elr;

    int d = idx[b];
    unsigned s = indptr[d];
    int deg = (int)(indptr[d + 1] - s);
    float2 erp = elr2[(size_t)d * 2 + 1];
    float er0 = erp.x, er1 = erp.y;

    float agg0 = 0.f, agg1 = 0.f;
    if (deg <= 64) {
        unsigned mysrc = 0;
        if (lane < deg) mysrc = csr[s + lane];
        float2 elp = elr2[(size_t)mysrc * 2];
        float e0 = elp.x + er0; e0 = e0 > 0.f ? e0 : 0.2f * e0;
        float e1 = elp.y + er1; e1 = e1 > 0.f ? e1 : 0.2f * e1;
        if (lane >= deg) { e0 = -1e30f; e1 = -1e30f; }
        float m0 = wave_max(e0), m1 = wave_max(e1);
        float p0 = (lane < deg) ? expf(e0 - m0) : 0.f;
        float p1 = (lane < deg) ? expf(e1 - m1) : 0.f;
        float sum0 = wave_sum(p0), sum1 = wave_sum(p1);
        float alpha0 = p0 * (1.0f / sum0);
        float alpha1 = p1 * (1.0f / sum1);

        for (int cb = 0; cb < deg; cb += 16) {
            float f[16];
#pragma unroll
            for (int jj = 0; jj < 16; ++jj) {
                int j2 = cb + jj;
                if (j2 < deg) {
                    unsigned sj = (unsigned)__builtin_amdgcn_readlane((int)mysrc, j2);
                    f[jj] = emb[(size_t)sj * 64 + lane];
                } else f[jj] = 0.f;
            }
#pragma unroll
            for (int jj = 0; jj < 16; ++jj) {
                int j2 = cb + jj;
                if (j2 < deg) {
                    agg0 = fmaf(rl_f32(alpha0, j2), f[jj], agg0);
                    agg1 = fmaf(rl_f32(alpha1, j2), f[jj], agg1);
                }
            }
        }
    } else {
        // slow path (deg > 64): 3-pass strided
        float m0 = -1e30f, m1 = -1e30f;
        for (int j = lane; j < deg; j += 64) {
            int src = (int)csr[s + j];
            float2 elp = elr2[(size_t)src * 2];
            float e0 = elp.x + er0; e0 = e0 > 0.f ? e0 : 0.2f * e0;
            float e1 = elp.y + er1; e1 = e1 > 0.f ? e1 : 0.2f * e1;
            m0 = fmaxf(m0, e0); m1 = fmaxf(m1, e1);
        }
        m0 = wave_max(m0); m1 = wave_max(m1);
        float s0 = 0.f, s1 = 0.f;
        for (int j = lane; j < deg; j += 64) {
            int src = (int)csr[s + j];
            float2 elp = elr2[(size_t)src * 2];
            float e0 = elp.x + er0; e0 = e0 > 0.f ? e0 : 0.2f * e0;
            float e1 = elp.y + er1; e1 = e1 > 0.f ? e1 : 0.2f * e1;
            s0 += expf(e0 - m0); s1 += expf(e1 - m1);
        }
        s0 = wave_sum(s0); s1 = wave_sum(s1);
        float r0 = 1.0f / s0, r1 = 1.0f / s1;
        for (int j = 0; j < deg; ++j) {
            int src = (int)csr[s + j];
            float2 elp = elr2[(size_t)src * 2];
            float e0 = elp.x + er0; e0 = e0 > 0.f ? e0 : 0.2f * e0;
            float e1 = elp.y + er1; e1 = e1 > 0.f ? e1 : 0.2f * e1;
            float a0 = expf(e0 - m0) * r0;
            float a1 = expf(e1 - m1) * r1;
            float f = emb[(size_t)src * 64 + lane];
            agg0 = fmaf(a0, f, agg0); agg1 = fmaf(a1, f, agg1);
        }
    }

    aggbuf[(size_t)row * 128 + lane] = agg0;
    aggbuf[(size_t)row * 128 + 64 + lane] = agg1;
}

// ---------------- proj: agg @ W + bias, LN, ELU, head-mean, +emb -> xbuf ----------------
// 256 threads, 4 waves; each wave processes 4 rows at a time (register-blocked).
#define PROJ_RPW 16  // rows per wave
__global__ __launch_bounds__(256) void proj_kernel(
    const int* __restrict__ uIdx, const float* __restrict__ u_W, const float* __restrict__ u_bias,
    const float* __restrict__ u_g, const float* __restrict__ u_b, const float* __restrict__ user_emb,
    const int* __restrict__ sIdx, const float* __restrict__ s_W, const float* __restrict__ s_bias,
    const float* __restrict__ s_g, const float* __restrict__ s_b, const float* __restrict__ serv_emb,
    const float* __restrict__ aggbuf, float* __restrict__ xbuf, int B, int nBlocksU) {
    __shared__ float2 Wp[64 * 64]; // 32KB: Wp[k*64+l] = (W[k][l], W[k][64+l])
    bool isU = (int)blockIdx.x < nBlocksU;
    const int* idx; const float* W; const float* bias; const float* g; const float* bb; const float* emb;
    int bbase;
    if (isU) { idx = uIdx; W = u_W; bias = u_bias; g = u_g; bb = u_b; emb = user_emb; bbase = (int)blockIdx.x; }
    else     { idx = sIdx; W = s_W; bias = s_bias; g = s_g; bb = s_b; emb = serv_emb; bbase = (int)blockIdx.x - nBlocksU; }
    for (int t = threadIdx.x; t < 4096; t += 256) {
        int k = t >> 6, l = t & 63;
        Wp[t] = make_float2(W[k * 128 + l], W[k * 128 + 64 + l]);
    }
    __syncthreads();

    int wid = threadIdx.x >> 6, lane = threadIdx.x & 63;
    int xoff = isU ? 0 : 64;
    int rowoff = isU ? 0 : B;
    float biasa = bias[lane], biasb = bias[64 + lane];
    float ga = g[lane], gb2 = g[64 + lane];
    float ba = bb[lane], bb2 = bb[64 + lane];

    int gwave = bbase * 4 + wid;
    int rstart = gwave * PROJ_RPW;
    for (int r0 = rstart; r0 < rstart + PROJ_RPW && r0 < B; r0 += 4) {
        float agg0[4], agg1[4], embv[4];
#pragma unroll
        for (int j = 0; j < 4; ++j) {
            int b = r0 + j;
            if (b < B) {
                int d = idx[b];
                embv[j] = emb[(size_t)d * 64 + lane];
                agg0[j] = aggbuf[(size_t)(rowoff + b) * 128 + lane];
                agg1[j] = aggbuf[(size_t)(rowoff + b) * 128 + 64 + lane];
            } else { embv[j] = 0.f; agg0[j] = 0.f; agg1[j] = 0.f; }
        }
        float acc0[4] = {0.f, 0.f, 0.f, 0.f}, acc1[4] = {0.f, 0.f, 0.f, 0.f};
#pragma unroll
        for (int k = 0; k < 64; ++k) {
            float2 w = Wp[k * 64 + lane];
#pragma unroll
            for (int j = 0; j < 4; ++j) {
                acc0[j] = fmaf(rl_f32(agg0[j], k), w.x, acc0[j]);
                acc1[j] = fmaf(rl_f32(agg1[j], k), w.y, acc1[j]);
            }
        }
#pragma unroll
        for (int j = 0; j < 4; ++j) {
            int b = r0 + j;
            if (b >= B) break;
            float o0 = acc0[j] + biasa, o1 = acc1[j] + biasb;
            float tot = wave_sum(o0 + o1);
            float mu = tot * (1.0f / 128.0f);
            float d0 = o0 - mu, d1 = o1 - mu;
            float var = wave_sum(d0 * d0 + d1 * d1) * (1.0f / 128.0f);
            float rstd = rsqrtf(var + 1e-5f);
            float l0 = d0 * rstd * ga + ba;
            float l1 = d1 * rstd * gb2 + bb2;
            l0 = l0 > 0.f ? l0 : expm1f(l0);
            l1 = l1 > 0.f ? l1 : expm1f(l1);
            float v = 0.5f * (l0 + l1) + embv[j];
            xbuf[(size_t)b * 128 + xoff + lane] = v;
        }
    }
}

// ---------------- MLP layer 1: out = relu(LN(in @ W + b)); 4-row register blocking ----------------
#define MLP_RPW 8
__global__ __launch_bounds__(256) void mlp_kernel(const float* __restrict__ xin, float* __restrict__ xout,
                                                  const float* __restrict__ W, const float* __restrict__ bvec,
                                                  const float* __restrict__ g, const float* __restrict__ bb,
                                                  int B) {
    __shared__ float2 Wp[128 * 64]; // 64KB
    for (int t = threadIdx.x; t < 8192; t += 256) {
        int k = t >> 6, l = t & 63;
        Wp[t] = make_float2(W[k * 128 + l], W[k * 128 + 64 + l]);
    }
    __syncthreads();
    int wid = threadIdx.x >> 6, lane = threadIdx.x & 63;
    int gwave = (int)blockIdx.x * 4 + wid;
    int rstart = gwave * MLP_RPW;
    for (int r0 = rstart; r0 < rstart + MLP_RPW && r0 < B; r0 += 4) {
        float x0[4], x1[4];
#pragma unroll
        for (int j = 0; j < 4; ++j) {
            int r = r0 + j;
            if (r < B) {
                x0[j] = xin[(size_t)r * 128 + lane];
                x1[j] = xin[(size_t)r * 128 + 64 + lane];
            } else { x0[j] = 0.f; x1[j] = 0.f; }
        }
        float acc0[4] = {0.f, 0.f, 0.f, 0.f}, acc1[4] = {0.f, 0.f, 0.f, 0.f};
#pragma unroll
        for (int k = 0; k < 64; ++k) {
            float2 w = Wp[k * 64 + lane];
#pragma unroll
            for (int j = 0; j < 4; ++j) {
                float xv = rl_f32(x0[j], k);
                acc0[j] = fmaf(xv, w.x, acc0[j]); acc1[j] = fmaf(xv, w.y, acc1[j]);
            }
        }
#pragma unroll
        for (int k = 0; k < 64; ++k) {
            float2 w = Wp[(64 + k) * 64 + lane];
#pragma unroll
            for (int j = 0; j < 4; ++j) {
                float xv = rl_f32(x1[j], k);
                acc0[j] = fmaf(xv, w.x, acc0[j]); acc1[j] = fmaf(xv, w.y, acc1[j]);
            }
        }
#pragma unroll
        for (int j = 0; j < 4; ++j) {
            int r = r0 + j;
            if (r >= B) break;
            float o0 = acc0[j] + bvec[lane], o1 = acc1[j] + bvec[64 + lane];
            float tot = wave_sum(o0 + o1);
            float mu = tot * (1.0f / 128.0f);
            float d0 = o0 - mu, d1 = o1 - mu;
            float var = wave_sum(d0 * d0 + d1 * d1) * (1.0f / 128.0f);
            float rstd = rsqrtf(var + 1e-5f);
            float l0 = d0 * rstd * g[lane] + bb[lane];
            float l1 = d1 * rstd * g[64 + lane] + bb[64 + lane];
            l0 = fmaxf(l0, 0.f); l1 = fmaxf(l1, 0.f);
            xout[(size_t)r * 128 + lane] = l0;
            xout[(size_t)r * 128 + 64 + lane] = l1;
        }
    }
}

// ---------------- MLP layer 2 fused with final dot + sigmoid; 4-row register blocking ----------------
__global__ __launch_bounds__(256) void mlpfin_kernel(const float* __restrict__ xin, float* __restrict__ out,
                                                     const float* __restrict__ W, const float* __restrict__ bvec,
                                                     const float* __restrict__ g, const float* __restrict__ bb,
                                                     const float* __restrict__ W3, const float* __restrict__ b3,
                                                     int B) {
    __shared__ float2 Wp[128 * 64]; // 64KB
    for (int t = threadIdx.x; t < 8192; t += 256) {
        int k = t >> 6, l = t & 63;
        Wp[t] = make_float2(W[k * 128 + l], W[k * 128 + 64 + l]);
    }
    __syncthreads();
    int wid = threadIdx.x >> 6, lane = threadIdx.x & 63;
    float w3a = W3[lane], w3b = W3[64 + lane];
    float b3v = b3[0];
    int gwave = (int)blockIdx.x * 4 + wid;
    int rstart = gwave * MLP_RPW;
    for (int r0 = rstart; r0 < rstart + MLP_RPW && r0 < B; r0 += 4) {
        float x0[4], x1[4];
#pragma unroll
        for (int j = 0; j < 4; ++j) {
            int r = r0 + j;
            if (r < B) {
                x0[j] = xin[(size_t)r * 128 + lane];
                x1[j] = xin[(size_t)r * 128 + 64 + lane];
            } else { x0[j] = 0.f; x1[j] = 0.f; }
        }
        float acc0[4] = {0.f, 0.f, 0.f, 0.f}, acc1[4] = {0.f, 0.f, 0.f, 0.f};
#pragma unroll
        for (int k = 0; k < 64; ++k) {
            float2 w = Wp[k * 64 + lane];
#pragma unroll
            for (int j = 0; j < 4; ++j) {
                float xv = rl_f32(x0[j], k);
                acc0[j] = fmaf(xv, w.x, acc0[j]); acc1[j] = fmaf(xv, w.y, acc1[j]);
            }
        }
#pragma unroll
        for (int k = 0; k < 64; ++k) {
            float2 w = Wp[(64 + k) * 64 + lane];
#pragma unroll
            for (int j = 0; j < 4; ++j) {
                float xv = rl_f32(x1[j], k);
                acc0[j] = fmaf(xv, w.x, acc0[j]); acc1[j] = fmaf(xv, w.y, acc1[j]);
            }
        }
#pragma unroll
        for (int j = 0; j < 4; ++j) {
            int r = r0 + j;
            if (r >= B) break;
            float o0 = acc0[j] + bvec[lane], o1 = acc1[j] + bvec[64 + lane];
            float tot = wave_sum(o0 + o1);
            float mu = tot * (1.0f / 128.0f);
            float d0 = o0 - mu, d1 = o1 - mu;
            float var = wave_sum(d0 * d0 + d1 * d1) * (1.0f / 128.0f);
            float rstd = rsqrtf(var + 1e-5f);
            float l0 = d0 * rstd * g[lane] + bb[lane];
            float l1 = d1 * rstd * g[64 + lane] + bb[64 + lane];
            l0 = fmaxf(l0, 0.f); l1 = fmaxf(l1, 0.f);
            float acc = wave_sum(fmaf(l0, w3a, l1 * w3b)) + b3v;
            if (lane == 0) out[r] = 1.0f / (1.0f + expf(-acc));
        }
    }
}

// ---------------- host launcher ----------------
extern "C" void kernel_launch(void* const* d_in, const int* in_sizes, int n_in,
                              void* d_out, int out_size, void* d_ws, size_t ws_size,
                              hipStream_t stream) {
    const int*   userIdx  = (const int*)d_in[0];
    const int*   servIdx  = (const int*)d_in[1];
    const int*   u_src    = (const int*)d_in[2];
    const int*   u_dst    = (const int*)d_in[3];
    const int*   s_src    = (const int*)d_in[4];
    const int*   s_dst    = (const int*)d_in[5];
    const float* user_emb = (const float*)d_in[6];
    const float* serv_emb = (const float*)d_in[7];
    const float* u_W      = (const float*)d_in[8];
    const float* u_al     = (const float*)d_in[9];
    const float* u_ar     = (const float*)d_in[10];
    const float* u_bias   = (const float*)d_in[11];
    const float* u_ln_g   = (const float*)d_in[12];
    const float* u_ln_b   = (const float*)d_in[13];
    const float* s_W      = (const float*)d_in[14];
    const float* s_al     = (const float*)d_in[15];
    const float* s_ar     = (const float*)d_in[16];
    const float* s_bias   = (const float*)d_in[17];
    const float* s_ln_g   = (const float*)d_in[18];
    const float* s_ln_b   = (const float*)d_in[19];
    const float* W1       = (const float*)d_in[20];
    const float* b1       = (const float*)d_in[21];
    const float* ln1_g    = (const float*)d_in[22];
    const float* ln1_b    = (const float*)d_in[23];
    const float* W2       = (const float*)d_in[24];
    const float* b2       = (const float*)d_in[25];
    const float* ln2_g    = (const float*)d_in[26];
    const float* ln2_b    = (const float*)d_in[27];
    const float* W3       = (const float*)d_in[28];
    const float* b3       = (const float*)d_in[29];

    const int B  = in_sizes[0];
    const int EU = in_sizes[2];
    const int ES = in_sizes[4];
    const int NU = in_sizes[6] / 64;
    const int NS = in_sizes[7] / 64;

    // workspace carve-up (256B aligned)
    char* w = (char*)d_ws;
    size_t off = 0;
    auto alloc = [&](size_t bytes) -> void* {
        void* p = w + off;
        off = (off + bytes + 255) & ~(size_t)255;
        return p;
    };
    unsigned* cnt_u    = (unsigned*)alloc((size_t)NU * 4);
    unsigned char* mark_u = (unsigned char*)alloc((size_t)NU);
    unsigned* indptr_u = (unsigned*)alloc((size_t)(NU + 1) * 4);
    unsigned* fill_u   = (unsigned*)alloc((size_t)NU * 4);
    unsigned* csr_u    = (unsigned*)alloc((size_t)EU * 4);
    unsigned* cnt_s    = (unsigned*)alloc((size_t)NS * 4);
    unsigned char* mark_s = (unsigned char*)alloc((size_t)NS);
    unsigned* indptr_s = (unsigned*)alloc((size_t)(NS + 1) * 4);
    unsigned* fill_s   = (unsigned*)alloc((size_t)NS * 4);
    unsigned* csr_s    = (unsigned*)alloc((size_t)ES * 4);
    unsigned* sums_u   = (unsigned*)alloc(256 * 4);
    unsigned* sums_s   = (unsigned*)alloc(256 * 4);
    float*    elr_u    = (float*)   alloc((size_t)NU * 4 * sizeof(float));
    float*    elr_s    = (float*)   alloc((size_t)NS * 4 * sizeof(float));
    float*    aggbuf   = (float*)   alloc((size_t)2 * B * 128 * sizeof(float));
    float*    xbuf     = (float*)   alloc((size_t)B * 128 * sizeof(float));
    float*    ybuf     = aggbuf;  // aggbuf is dead after proj; reuse for MLP intermediate
    (void)ws_size;

    const int nbU = (NU + SCAN_TILE - 1) / SCAN_TILE;
    const int nbS = (NS + SCAN_TILE - 1) / SCAN_TILE;
    const int totN = NU + NS;
    const int totE = EU + ES;

    zero_kernel<<<(totN + 255) / 256, 256, 0, stream>>>(cnt_u, mark_u, NU, cnt_s, mark_s, NS);
    mark_kernel<<<(2 * B + 255) / 256, 256, 0, stream>>>(userIdx, mark_u, servIdx, mark_s, B);
    count_kernel<<<(totE + 255) / 256, 256, 0, stream>>>(u_dst, EU, cnt_u, mark_u,
                                                         s_dst, ES, cnt_s, mark_s);
    scan1_kernel<<<nbU + nbS, SCAN_TPB, 0, stream>>>(cnt_u, indptr_u, sums_u, NU, nbU,
                                                     cnt_s, indptr_s, sums_s, NS);
    scanf_kernel<<<nbU + nbS, SCAN_TPB, 0, stream>>>(cnt_u, indptr_u, fill_u, sums_u, NU, nbU,
                                                     cnt_s, indptr_s, fill_s, sums_s, NS);
    scatter_kernel<<<(totE + 255) / 256, 256, 0, stream>>>(u_src, u_dst, EU, fill_u, csr_u, mark_u,
                                                           s_src, s_dst, ES, fill_s, csr_s, mark_s);
    eler_kernel<<<(totN + 255) / 256, 256, 0, stream>>>(u_W, u_al, u_ar, s_W, s_al, s_ar,
                                                        user_emb, (float4*)elr_u, NU,
                                                        serv_emb, (float4*)elr_s, NS);
    const int nBlocksU = (B + 3) / 4;
    gather_kernel<<<2 * nBlocksU, 256, 0, stream>>>(
        userIdx, indptr_u, csr_u, elr_u, user_emb,
        servIdx, indptr_s, csr_s, elr_s, serv_emb,
        aggbuf, B, nBlocksU);
    const int nPB = (B + 4 * PROJ_RPW - 1) / (4 * PROJ_RPW);
    proj_kernel<<<2 * nPB, 256, 0, stream>>>(
        userIdx, u_W, u_bias, u_ln_g, u_ln_b, user_emb,
        servIdx, s_W, s_bias, s_ln_g, s_ln_b, serv_emb,
        aggbuf, xbuf, B, nPB);
    const int nMB = (B + 4 * MLP_RPW - 1) / (4 * MLP_RPW);
    mlp_kernel<<<nMB, 256, 0, stream>>>(xbuf, ybuf, W1, b1, ln1_g, ln1_b, B);
    mlpfin_kernel<<<nMB, 256, 0, stream>>>(ybuf, (float*)d_out, W2, b2, ln2_g, ln2_b, W3, b3, B);
}

// Round 8
// 388.708 us; speedup vs baseline: 1.8495x; 1.0785x over previous
//
#include <hip/hip_runtime.h>
#include <cstdint>
#include <cstddef>

// ---------------- wave helpers ----------------
__device__ __forceinline__ float wave_sum(float v) {
#pragma unroll
    for (int o = 32; o > 0; o >>= 1) v += __shfl_xor(v, o, 64);
    return v;
}
__device__ __forceinline__ unsigned wave_sum_u32(unsigned v) {
#pragma unroll
    for (int o = 32; o > 0; o >>= 1) v += (unsigned)__shfl_xor((int)v, o, 64);
    return v;
}
__device__ __forceinline__ float wave_max(float v) {
#pragma unroll
    for (int o = 32; o > 0; o >>= 1) v = fmaxf(v, __shfl_xor(v, o, 64));
    return v;
}
__device__ __forceinline__ float rl_f32(float v, int lane) {
    return __uint_as_float((unsigned)__builtin_amdgcn_readlane((int)__float_as_uint(v), lane));
}

// ---------------- zero counters + marks ----------------
__global__ void zero_kernel(unsigned* __restrict__ cnt_u, unsigned char* __restrict__ mark_u, int nU,
                            unsigned* __restrict__ cnt_s, unsigned char* __restrict__ mark_s, int nS) {
    int i = blockIdx.x * blockDim.x + threadIdx.x;
    int tot = nU + nS;
    if (i >= tot) return;
    if (i < nU) { cnt_u[i] = 0u; mark_u[i] = 0; }
    else        { cnt_s[i - nU] = 0u; mark_s[i - nU] = 0; }
}

// ---------------- mark requested destinations ----------------
__global__ void mark_kernel(const int* __restrict__ uIdx, unsigned char* __restrict__ mark_u,
                            const int* __restrict__ sIdx, unsigned char* __restrict__ mark_s, int B) {
    int t = blockIdx.x * blockDim.x + threadIdx.x;
    if (t < B)          mark_u[uIdx[t]] = 1;
    else if (t < 2 * B) mark_s[sIdx[t - B]] = 1;
}

// ---------------- count in-degree (requested dsts only) ----------------
__global__ void count_kernel(const int* __restrict__ u_dst, int EU, unsigned* __restrict__ cnt_u,
                             const unsigned char* __restrict__ mark_u,
                             const int* __restrict__ s_dst, int ES, unsigned* __restrict__ cnt_s,
                             const unsigned char* __restrict__ mark_s) {
    int e = blockIdx.x * blockDim.x + threadIdx.x;
    int tot = EU + ES;
    if (e >= tot) return;
    if (e < EU) {
        int d = u_dst[e];
        if (mark_u[d]) atomicAdd(&cnt_u[d], 1u);
    } else {
        int d = s_dst[e - EU];
        if (mark_s[d]) atomicAdd(&cnt_s[d], 1u);
    }
}

// ---------------- scan phase 1 ----------------
#define SCAN_TPB 256
#define SCAN_VPT 8
#define SCAN_TILE 2048

__global__ __launch_bounds__(SCAN_TPB) void scan1_kernel(
    const unsigned* __restrict__ cnt_u, unsigned* __restrict__ indptr_u, unsigned* __restrict__ sums_u, int nU, int nbU,
    const unsigned* __restrict__ cnt_s, unsigned* __restrict__ indptr_s, unsigned* __restrict__ sums_s, int nS) {
    int b = (int)blockIdx.x;
    const unsigned* cnt; unsigned* indptr; unsigned* sums; int n, tile;
    if (b < nbU) { cnt = cnt_u; indptr = indptr_u; sums = sums_u; n = nU; tile = b; }
    else         { cnt = cnt_s; indptr = indptr_s; sums = sums_s; n = nS; tile = b - nbU; }
    int base = tile * SCAN_TILE + (int)threadIdx.x * SCAN_VPT;
    unsigned v[SCAN_VPT];
#pragma unroll
    for (int j = 0; j < SCAN_VPT; ++j) { int i = base + j; v[j] = (i < n) ? cnt[i] : 0u; }
#pragma unroll
    for (int j = 1; j < SCAN_VPT; ++j) v[j] += v[j - 1];
    __shared__ unsigned sh[SCAN_TPB];
    sh[threadIdx.x] = v[SCAN_VPT - 1];
    __syncthreads();
    for (int d = 1; d < SCAN_TPB; d <<= 1) {
        unsigned t = (threadIdx.x >= (unsigned)d) ? sh[threadIdx.x - d] : 0u;
        __syncthreads();
        sh[threadIdx.x] += t;
        __syncthreads();
    }
    unsigned prefix = (threadIdx.x > 0) ? sh[threadIdx.x - 1] : 0u;
#pragma unroll
    for (int j = 0; j < SCAN_VPT; ++j) { int i = base + j; if (i < n) indptr[i + 1] = v[j] + prefix; }
    if (threadIdx.x == SCAN_TPB - 1) sums[tile] = sh[SCAN_TPB - 1];
}

// ---------------- scan phase 2+3 fused ----------------
__global__ __launch_bounds__(SCAN_TPB) void scanf_kernel(
    const unsigned* __restrict__ cnt_u, unsigned* __restrict__ indptr_u, unsigned* __restrict__ fill_u,
    const unsigned* __restrict__ sums_u, int nU, int nbU,
    const unsigned* __restrict__ cnt_s, unsigned* __restrict__ indptr_s, unsigned* __restrict__ fill_s,
    const unsigned* __restrict__ sums_s, int nS) {
    int b = (int)blockIdx.x;
    const unsigned* cnt; unsigned* indptr; unsigned* fill; const unsigned* sums; int n, tile;
    if (b < nbU) { cnt = cnt_u; indptr = indptr_u; fill = fill_u; sums = sums_u; n = nU; tile = b; }
    else         { cnt = cnt_s; indptr = indptr_s; fill = fill_s; sums = sums_s; n = nS; tile = b - nbU; }
    int lane = threadIdx.x & 63;
    unsigned a0 = (lane < tile) ? sums[lane] : 0u;
    unsigned a1 = (lane + 64 < tile) ? sums[lane + 64] : 0u;
    unsigned off = wave_sum_u32(a0 + a1);
    int base = tile * SCAN_TILE + (int)threadIdx.x * SCAN_VPT;
#pragma unroll
    for (int j = 0; j < SCAN_VPT; ++j) {
        int i = base + j;
        if (i < n) {
            unsigned incl = indptr[i + 1] + off;
            indptr[i + 1] = incl;
            fill[i] = incl - cnt[i];
        }
    }
    if (b == 0 && threadIdx.x == 0) { indptr_u[0] = 0u; indptr_s[0] = 0u; }
}

// ---------------- scatter edges into CSR (requested dsts only) ----------------
__global__ void scatter_kernel(const int* __restrict__ u_src, const int* __restrict__ u_dst, int EU,
                               unsigned* __restrict__ fill_u, unsigned* __restrict__ csr_u,
                               const unsigned char* __restrict__ mark_u,
                               const int* __restrict__ s_src, const int* __restrict__ s_dst, int ES,
                               unsigned* __restrict__ fill_s, unsigned* __restrict__ csr_s,
                               const unsigned char* __restrict__ mark_s) {
    int e = blockIdx.x * blockDim.x + threadIdx.x;
    int tot = EU + ES;
    if (e >= tot) return;
    if (e < EU) {
        int d = u_dst[e];
        if (mark_u[d]) {
            unsigned pos = atomicAdd(&fill_u[d], 1u);
            csr_u[pos] = (unsigned)u_src[e];
        }
    } else {
        int ee = e - EU;
        int d = s_dst[ee];
        if (mark_s[d]) {
            unsigned pos = atomicAdd(&fill_s[d], 1u);
            csr_s[pos] = (unsigned)s_src[ee];
        }
    }
}

// ---------------- el/er for all nodes (wq computed in-block in LDS) ----------------
__global__ __launch_bounds__(256) void eler_kernel(
    const float* __restrict__ u_W, const float* __restrict__ u_al, const float* __restrict__ u_ar,
    const float* __restrict__ s_W, const float* __restrict__ s_al, const float* __restrict__ s_ar,
    const float* __restrict__ user_emb, float4* __restrict__ elr_u, int nU,
    const float* __restrict__ serv_emb, float4* __restrict__ elr_s, int nS) {
    __shared__ float4 wq[128]; // [0..64) user, [64..128) serv
    int t = threadIdx.x;
    if (t < 128) {
        const float* W  = (t < 64) ? u_W : s_W;
        const float* al = (t < 64) ? u_al : s_al;
        const float* ar = (t < 64) ? u_ar : s_ar;
        int k = t & 63;
        float a0 = 0.f, a1 = 0.f, a2 = 0.f, a3 = 0.f;
        for (int d = 0; d < 64; ++d) {
            float w0 = W[k * 128 + d], w1 = W[k * 128 + 64 + d];
            a0 += w0 * al[d];      a1 += w1 * al[64 + d];
            a2 += w0 * ar[d];      a3 += w1 * ar[64 + d];
        }
        wq[t] = make_float4(a0, a1, a2, a3);
    }
    __syncthreads();
    int n = blockIdx.x * 256 + t;
    int tot = nU + nS;
    if (n >= tot) return;
    const float* feat; const float4* wqp; float4* elr; int i;
    if (n < nU) { i = n;      feat = user_emb + (size_t)i * 64; wqp = wq;      elr = elr_u; }
    else        { i = n - nU; feat = serv_emb + (size_t)i * 64; wqp = wq + 64; elr = elr_s; }
    float a0 = 0.f, a1 = 0.f, a2 = 0.f, a3 = 0.f;
    const float4* f4 = (const float4*)feat;
#pragma unroll
    for (int q = 0; q < 16; ++q) {
        float4 f = f4[q];
        float4 w;
        w = wqp[q * 4 + 0]; a0 = fmaf(f.x, w.x, a0); a1 = fmaf(f.x, w.y, a1); a2 = fmaf(f.x, w.z, a2); a3 = fmaf(f.x, w.w, a3);
        w = wqp[q * 4 + 1]; a0 = fmaf(f.y, w.x, a0); a1 = fmaf(f.y, w.y, a1); a2 = fmaf(f.y, w.z, a2); a3 = fmaf(f.y, w.w, a3);
        w = wqp[q * 4 + 2]; a0 = fmaf(f.z, w.x, a0); a1 = fmaf(f.z, w.y, a1); a2 = fmaf(f.z, w.z, a2); a3 = fmaf(f.z, w.w, a3);
        w = wqp[q * 4 + 3]; a0 = fmaf(f.w, w.x, a0); a1 = fmaf(f.w, w.y, a1); a2 = fmaf(f.w, w.z, a2); a3 = fmaf(f.w, w.w, a3);
    }
    elr[i] = make_float4(a0, a1, a2, a3);
}

// ---------------- gather: attention softmax + alpha-weighted feature aggregation ----------------
__global__ __launch_bounds__(256, 4) void gather_kernel(
    const int* __restrict__ uIdx, const unsigned* __restrict__ indptr_u, const unsigned* __restrict__ csr_u,
    const float* __restrict__ elr_u, const float* __restrict__ user_emb,
    const int* __restrict__ sIdx, const unsigned* __restrict__ indptr_s, const unsigned* __restrict__ csr_s,
    const float* __restrict__ elr_s, const float* __restrict__ serv_emb,
    float* __restrict__ aggbuf, int B, int nBlocksU) {
    bool isU = (int)blockIdx.x < nBlocksU;
    const int* idx; const unsigned* indptr; const unsigned* csr; const float* elr; const float* emb;
    int bb4 = isU ? (int)blockIdx.x : (int)blockIdx.x - nBlocksU;
    if (isU) { idx = uIdx; indptr = indptr_u; csr = csr_u; elr = elr_u; emb = user_emb; }
    else     { idx = sIdx; indptr = indptr_s; csr = csr_s; elr = elr_s; emb = serv_emb; }
    int wid = threadIdx.x >> 6, lane = threadIdx.x & 63;
    int b = bb4 * 4 + wid;
    if (b >= B) return;
    int row = isU ? b : B + b;
    const float2* elr2 = (const float2*)elr;

    int d = idx[b];
    unsigned s = indptr[d];
    int deg = (int)(indptr[d + 1] - s);
    float2 erp = elr2[(size_t)d * 2 + 1];
    float er0 = erp.x, er1 = erp.y;

    float agg0 = 0.f, agg1 = 0.f;
    if (deg <= 64) {
        unsigned mysrc = 0;
        if (lane < deg) mysrc = csr[s + lane];
        float2 elp = elr2[(size_t)mysrc * 2];
        float e0 = elp.x + er0; e0 = e0 > 0.f ? e0 : 0.2f * e0;
        float e1 = elp.y + er1; e1 = e1 > 0.f ? e1 : 0.2f * e1;
        if (lane >= deg) { e0 = -1e30f; e1 = -1e30f; }
        float m0 = wave_max(e0), m1 = wave_max(e1);
        float p0 = (lane < deg) ? expf(e0 - m0) : 0.f;
        float p1 = (lane < deg) ? expf(e1 - m1) : 0.f;
        float sum0 = wave_sum(p0), sum1 = wave_sum(p1);
        float alpha0 = p0 * (1.0f / sum0);
        float alpha1 = p1 * (1.0f / sum1);

        for (int cb = 0; cb < deg; cb += 16) {
            float f[16];
#pragma unroll
            for (int jj = 0; jj < 16; ++jj) {
                int j2 = cb + jj;
                if (j2 < deg) {
                    unsigned sj = (unsigned)__builtin_amdgcn_readlane((int)mysrc, j2);
                    f[jj] = emb[(size_t)sj * 64 + lane];
                } else f[jj] = 0.f;
            }
#pragma unroll
            for (int jj = 0; jj < 16; ++jj) {
                int j2 = cb + jj;
                if (j2 < deg) {
                    agg0 = fmaf(rl_f32(alpha0, j2), f[jj], agg0);
                    agg1 = fmaf(rl_f32(alpha1, j2), f[jj], agg1);
                }
            }
        }
    } else {
        float m0 = -1e30f, m1 = -1e30f;
        for (int j = lane; j < deg; j += 64) {
            int src = (int)csr[s + j];
            float2 elp = elr2[(size_t)src * 2];
            float e0 = elp.x + er0; e0 = e0 > 0.f ? e0 : 0.2f * e0;
            float e1 = elp.y + er1; e1 = e1 > 0.f ? e1 : 0.2f * e1;
            m0 = fmaxf(m0, e0); m1 = fmaxf(m1, e1);
        }
        m0 = wave_max(m0); m1 = wave_max(m1);
        float s0 = 0.f, s1 = 0.f;
        for (int j = lane; j < deg; j += 64) {
            int src = (int)csr[s + j];
            float2 elp = elr2[(size_t)src * 2];
            float e0 = elp.x + er0; e0 = e0 > 0.f ? e0 : 0.2f * e0;
            float e1 = elp.y + er1; e1 = e1 > 0.f ? e1 : 0.2f * e1;
            s0 += expf(e0 - m0); s1 += expf(e1 - m1);
        }
        s0 = wave_sum(s0); s1 = wave_sum(s1);
        float r0 = 1.0f / s0, r1 = 1.0f / s1;
        for (int j = 0; j < deg; ++j) {
            int src = (int)csr[s + j];
            float2 elp = elr2[(size_t)src * 2];
            float e0 = elp.x + er0; e0 = e0 > 0.f ? e0 : 0.2f * e0;
            float e1 = elp.y + er1; e1 = e1 > 0.f ? e1 : 0.2f * e1;
            float a0 = expf(e0 - m0) * r0;
            float a1 = expf(e1 - m1) * r1;
            float f = emb[(size_t)src * 64 + lane];
            agg0 = fmaf(a0, f, agg0); agg1 = fmaf(a1, f, agg1);
        }
    }

    aggbuf[(size_t)row * 128 + lane] = agg0;
    aggbuf[(size_t)row * 128 + 64 + lane] = agg1;
}

// ---------------- proj: x-in-LDS, W streamed from L1/L2; K=64 ----------------
// Block = 256 thr (4 waves), 16 rows/block (4 rows/wave). Lane owns out cols (lane, 64+lane).
#define PROJ_ROWS 16
__global__ __launch_bounds__(256) void proj_kernel(
    const int* __restrict__ uIdx, const float* __restrict__ u_W, const float* __restrict__ u_bias,
    const float* __restrict__ u_g, const float* __restrict__ u_b, const float* __restrict__ user_emb,
    const int* __restrict__ sIdx, const float* __restrict__ s_W, const float* __restrict__ s_bias,
    const float* __restrict__ s_g, const float* __restrict__ s_b, const float* __restrict__ serv_emb,
    const float* __restrict__ aggbuf, float* __restrict__ xbuf, int B, int nPB) {
    __shared__ __align__(16) float xs[PROJ_ROWS][128]; // 8KB
    bool isU = (int)blockIdx.x < nPB;
    const int* idx; const float* W; const float* bias; const float* g; const float* bb; const float* emb;
    int blk = isU ? (int)blockIdx.x : (int)blockIdx.x - nPB;
    if (isU) { idx = uIdx; W = u_W; bias = u_bias; g = u_g; bb = u_b; emb = user_emb; }
    else     { idx = sIdx; W = s_W; bias = s_bias; g = s_g; bb = s_b; emb = serv_emb; }
    int r0 = blk * PROJ_ROWS;
    int rowoff = isU ? 0 : B;

    // stage 16 aggbuf rows (contiguous) into LDS
    {
        const float4* src4 = (const float4*)(aggbuf + (size_t)(rowoff + r0) * 128);
        float4* xs4 = (float4*)xs;
#pragma unroll
        for (int i = 0; i < 2; ++i) xs4[threadIdx.x + i * 256] = src4[threadIdx.x + i * 256];
    }

    int wid = threadIdx.x >> 6, lane = threadIdx.x & 63;
    int xoff = isU ? 0 : 64;

    // prefetch dst rows' emb (random gather) while LDS settles
    float embv[4]; int rb[4];
#pragma unroll
    for (int j = 0; j < 4; ++j) {
        rb[j] = r0 + wid * 4 + j;
        int d = (rb[j] < B) ? idx[rb[j]] : 0;
        embv[j] = emb[(size_t)d * 64 + lane];
    }
    __syncthreads();

    float acc0[4] = {0.f, 0.f, 0.f, 0.f}, acc1[4] = {0.f, 0.f, 0.f, 0.f};
    for (int kq = 0; kq < 16; ++kq) {
        float w0[4], w1[4];
#pragma unroll
        for (int i = 0; i < 4; ++i) {
            w0[i] = W[(kq * 4 + i) * 128 + lane];
            w1[i] = W[(kq * 4 + i) * 128 + 64 + lane];
        }
#pragma unroll
        for (int j = 0; j < 4; ++j) {
            int r = wid * 4 + j;
            float4 xa = *(const float4*)&xs[r][kq * 4];        // head-0 inputs (broadcast)
            float4 xb = *(const float4*)&xs[r][64 + kq * 4];   // head-1 inputs
            acc0[j] = fmaf(xa.x, w0[0], acc0[j]); acc0[j] = fmaf(xa.y, w0[1], acc0[j]);
            acc0[j] = fmaf(xa.z, w0[2], acc0[j]); acc0[j] = fmaf(xa.w, w0[3], acc0[j]);
            acc1[j] = fmaf(xb.x, w1[0], acc1[j]); acc1[j] = fmaf(xb.y, w1[1], acc1[j]);
            acc1[j] = fmaf(xb.z, w1[2], acc1[j]); acc1[j] = fmaf(xb.w, w1[3], acc1[j]);
        }
    }

    float biasa = bias[lane], biasb = bias[64 + lane];
    float ga = g[lane], gb2 = g[64 + lane];
    float ba = bb[lane], bb2 = bb[64 + lane];
#pragma unroll
    for (int j = 0; j < 4; ++j) {
        if (rb[j] >= B) break;
        float o0 = acc0[j] + biasa, o1 = acc1[j] + biasb;
        float tot = wave_sum(o0 + o1);
        float mu = tot * (1.0f / 128.0f);
        float d0 = o0 - mu, d1 = o1 - mu;
        float var = wave_sum(d0 * d0 + d1 * d1) * (1.0f / 128.0f);
        float rstd = rsqrtf(var + 1e-5f);
        float l0 = d0 * rstd * ga + ba;
        float l1 = d1 * rstd * gb2 + bb2;
        l0 = l0 > 0.f ? l0 : expm1f(l0);
        l1 = l1 > 0.f ? l1 : expm1f(l1);
        xbuf[(size_t)rb[j] * 128 + xoff + lane] = 0.5f * (l0 + l1) + embv[j];
    }
}

// ---------------- MLP layer 1: x-in-LDS, W streamed; K=128 ----------------
#define MLP_ROWS 16
__global__ __launch_bounds__(256) void mlp_kernel(const float* __restrict__ xin, float* __restrict__ xout,
                                                  const float* __restrict__ W, const float* __restrict__ bvec,
                                                  const float* __restrict__ g, const float* __restrict__ bb,
                                                  int B) {
    __shared__ __align__(16) float xs[MLP_ROWS][128]; // 8KB
    int r0 = (int)blockIdx.x * MLP_ROWS;
    {
        const float4* src4 = (const float4*)(xin + (size_t)r0 * 128);
        float4* xs4 = (float4*)xs;
#pragma unroll
        for (int i = 0; i < 2; ++i) xs4[threadIdx.x + i * 256] = src4[threadIdx.x + i * 256];
    }
    __syncthreads();
    int wid = threadIdx.x >> 6, lane = threadIdx.x & 63;

    float acc0[4] = {0.f, 0.f, 0.f, 0.f}, acc1[4] = {0.f, 0.f, 0.f, 0.f};
    for (int kq = 0; kq < 32; ++kq) {
        float w0[4], w1[4];
#pragma unroll
        for (int i = 0; i < 4; ++i) {
            w0[i] = W[(kq * 4 + i) * 128 + lane];
            w1[i] = W[(kq * 4 + i) * 128 + 64 + lane];
        }
#pragma unroll
        for (int j = 0; j < 4; ++j) {
            int r = wid * 4 + j;
            float4 xq = *(const float4*)&xs[r][kq * 4];  // broadcast
            acc0[j] = fmaf(xq.x, w0[0], acc0[j]); acc1[j] = fmaf(xq.x, w1[0], acc1[j]);
            acc0[j] = fmaf(xq.y, w0[1], acc0[j]); acc1[j] = fmaf(xq.y, w1[1], acc1[j]);
            acc0[j] = fmaf(xq.z, w0[2], acc0[j]); acc1[j] = fmaf(xq.z, w1[2], acc1[j]);
            acc0[j] = fmaf(xq.w, w0[3], acc0[j]); acc1[j] = fmaf(xq.w, w1[3], acc1[j]);
        }
    }

    float bva = bvec[lane], bvb = bvec[64 + lane];
    float ga = g[lane], gb2 = g[64 + lane];
    float ba = bb[lane], bb2 = bb[64 + lane];
#pragma unroll
    for (int j = 0; j < 4; ++j) {
        int r = r0 + wid * 4 + j;
        if (r >= B) break;
        float o0 = acc0[j] + bva, o1 = acc1[j] + bvb;
        float tot = wave_sum(o0 + o1);
        float mu = tot * (1.0f / 128.0f);
        float d0 = o0 - mu, d1 = o1 - mu;
        float var = wave_sum(d0 * d0 + d1 * d1) * (1.0f / 128.0f);
        float rstd = rsqrtf(var + 1e-5f);
        float l0 = d0 * rstd * ga + ba;
        float l1 = d1 * rstd * gb2 + bb2;
        l0 = fmaxf(l0, 0.f); l1 = fmaxf(l1, 0.f);
        xout[(size_t)r * 128 + lane] = l0;
        xout[(size_t)r * 128 + 64 + lane] = l1;
    }
}

// ---------------- MLP layer 2 + final dot + sigmoid ----------------
__global__ __launch_bounds__(256) void mlpfin_kernel(const float* __restrict__ xin, float* __restrict__ out,
                                                     const float* __restrict__ W, const float* __restrict__ bvec,
                                                     const float* __restrict__ g, const float* __restrict__ bb,
                                                     const float* __restrict__ W3, const float* __restrict__ b3,
                                                     int B) {
    __shared__ __align__(16) float xs[MLP_ROWS][128]; // 8KB
    int r0 = (int)blockIdx.x * MLP_ROWS;
    {
        const float4* src4 = (const float4*)(xin + (size_t)r0 * 128);
        float4* xs4 = (float4*)xs;
#pragma unroll
        for (int i = 0; i < 2; ++i) xs4[threadIdx.x + i * 256] = src4[threadIdx.x + i * 256];
    }
    __syncthreads();
    int wid = threadIdx.x >> 6, lane = threadIdx.x & 63;

    float acc0[4] = {0.f, 0.f, 0.f, 0.f}, acc1[4] = {0.f, 0.f, 0.f, 0.f};
    for (int kq = 0; kq < 32; ++kq) {
        float w0[4], w1[4];
#pragma unroll
        for (int i = 0; i < 4; ++i) {
            w0[i] = W[(kq * 4 + i) * 128 + lane];
            w1[i] = W[(kq * 4 + i) * 128 + 64 + lane];
        }
#pragma unroll
        for (int j = 0; j < 4; ++j) {
            int r = wid * 4 + j;
            float4 xq = *(const float4*)&xs[r][kq * 4];
            acc0[j] = fmaf(xq.x, w0[0], acc0[j]); acc1[j] = fmaf(xq.x, w1[0], acc1[j]);
            acc0[j] = fmaf(xq.y, w0[1], acc0[j]); acc1[j] = fmaf(xq.y, w1[1], acc1[j]);
            acc0[j] = fmaf(xq.z, w0[2], acc0[j]); acc1[j] = fmaf(xq.z, w1[2], acc1[j]);
            acc0[j] = fmaf(xq.w, w0[3], acc0[j]); acc1[j] = fmaf(xq.w, w1[3], acc1[j]);
        }
    }

    float bva = bvec[lane], bvb = bvec[64 + lane];
    float ga = g[lane], gb2 = g[64 + lane];
    float ba = bb[lane], bb2 = bb[64 + lane];
    float w3a = W3[lane], w3b = W3[64 + lane];
    float b3v = b3[0];
#pragma unroll
    for (int j = 0; j < 4; ++j) {
        int r = r0 + wid * 4 + j;
        if (r >= B) break;
        float o0 = acc0[j] + bva, o1 = acc1[j] + bvb;
        float tot = wave_sum(o0 + o1);
        float mu = tot * (1.0f / 128.0f);
        float d0 = o0 - mu, d1 = o1 - mu;
        float var = wave_sum(d0 * d0 + d1 * d1) * (1.0f / 128.0f);
        float rstd = rsqrtf(var + 1e-5f);
        float l0 = d0 * rstd * ga + ba;
        float l1 = d1 * rstd * gb2 + bb2;
        l0 = fmaxf(l0, 0.f); l1 = fmaxf(l1, 0.f);
        float acc = wave_sum(fmaf(l0, w3a, l1 * w3b)) + b3v;
        if (lane == 0) out[r] = 1.0f / (1.0f + expf(-acc));
    }
}

// ---------------- host launcher ----------------
extern "C" void kernel_launch(void* const* d_in, const int* in_sizes, int n_in,
                              void* d_out, int out_size, void* d_ws, size_t ws_size,
                              hipStream_t stream) {
    const int*   userIdx  = (const int*)d_in[0];
    const int*   servIdx  = (const int*)d_in[1];
    const int*   u_src    = (const int*)d_in[2];
    const int*   u_dst    = (const int*)d_in[3];
    const int*   s_src    = (const int*)d_in[4];
    const int*   s_dst    = (const int*)d_in[5];
    const float* user_emb = (const float*)d_in[6];
    const float* serv_emb = (const float*)d_in[7];
    const float* u_W      = (const float*)d_in[8];
    const float* u_al     = (const float*)d_in[9];
    const float* u_ar     = (const float*)d_in[10];
    const float* u_bias   = (const float*)d_in[11];
    const float* u_ln_g   = (const float*)d_in[12];
    const float* u_ln_b   = (const float*)d_in[13];
    const float* s_W      = (const float*)d_in[14];
    const float* s_al     = (const float*)d_in[15];
    const float* s_ar     = (const float*)d_in[16];
    const float* s_bias   = (const float*)d_in[17];
    const float* s_ln_g   = (const float*)d_in[18];
    const float* s_ln_b   = (const float*)d_in[19];
    const float* W1       = (const float*)d_in[20];
    const float* b1       = (const float*)d_in[21];
    const float* ln1_g    = (const float*)d_in[22];
    const float* ln1_b    = (const float*)d_in[23];
    const float* W2       = (const float*)d_in[24];
    const float* b2       = (const float*)d_in[25];
    const float* ln2_g    = (const float*)d_in[26];
    const float* ln2_b    = (const float*)d_in[27];
    const float* W3       = (const float*)d_in[28];
    const float* b3       = (const float*)d_in[29];

    const int B  = in_sizes[0];
    const int EU = in_sizes[2];
    const int ES = in_sizes[4];
    const int NU = in_sizes[6] / 64;
    const int NS = in_sizes[7] / 64;

    // workspace carve-up (256B aligned)
    char* w = (char*)d_ws;
    size_t off = 0;
    auto alloc = [&](size_t bytes) -> void* {
        void* p = w + off;
        off = (off + bytes + 255) & ~(size_t)255;
        return p;
    };
    unsigned* cnt_u    = (unsigned*)alloc((size_t)NU * 4);
    unsigned char* mark_u = (unsigned char*)alloc((size_t)NU);
    unsigned* indptr_u = (unsigned*)alloc((size_t)(NU + 1) * 4);
    unsigned* fill_u   = (unsigned*)alloc((size_t)NU * 4);
    unsigned* csr_u    = (unsigned*)alloc((size_t)EU * 4);
    unsigned* cnt_s    = (unsigned*)alloc((size_t)NS * 4);
    unsigned char* mark_s = (unsigned char*)alloc((size_t)NS);
    unsigned* indptr_s = (unsigned*)alloc((size_t)(NS + 1) * 4);
    unsigned* fill_s   = (unsigned*)alloc((size_t)NS * 4);
    unsigned* csr_s    = (unsigned*)alloc((size_t)ES * 4);
    unsigned* sums_u   = (unsigned*)alloc(256 * 4);
    unsigned* sums_s   = (unsigned*)alloc(256 * 4);
    float*    elr_u    = (float*)   alloc((size_t)NU * 4 * sizeof(float));
    float*    elr_s    = (float*)   alloc((size_t)NS * 4 * sizeof(float));
    float*    aggbuf   = (float*)   alloc((size_t)2 * B * 128 * sizeof(float));
    float*    xbuf     = (float*)   alloc((size_t)B * 128 * sizeof(float));
    float*    ybuf     = aggbuf;  // aggbuf dead after proj; reuse for MLP intermediate
    (void)ws_size;

    const int nbU = (NU + SCAN_TILE - 1) / SCAN_TILE;
    const int nbS = (NS + SCAN_TILE - 1) / SCAN_TILE;
    const int totN = NU + NS;
    const int totE = EU + ES;

    zero_kernel<<<(totN + 255) / 256, 256, 0, stream>>>(cnt_u, mark_u, NU, cnt_s, mark_s, NS);
    mark_kernel<<<(2 * B + 255) / 256, 256, 0, stream>>>(userIdx, mark_u, servIdx, mark_s, B);
    count_kernel<<<(totE + 255) / 256, 256, 0, stream>>>(u_dst, EU, cnt_u, mark_u,
                                                         s_dst, ES, cnt_s, mark_s);
    scan1_kernel<<<nbU + nbS, SCAN_TPB, 0, stream>>>(cnt_u, indptr_u, sums_u, NU, nbU,
                                                     cnt_s, indptr_s, sums_s, NS);
    scanf_kernel<<<nbU + nbS, SCAN_TPB, 0, stream>>>(cnt_u, indptr_u, fill_u, sums_u, NU, nbU,
                                                     cnt_s, indptr_s, fill_s, sums_s, NS);
    scatter_kernel<<<(totE + 255) / 256, 256, 0, stream>>>(u_src, u_dst, EU, fill_u, csr_u, mark_u,
                                                           s_src, s_dst, ES, fill_s, csr_s, mark_s);
    eler_kernel<<<(totN + 255) / 256, 256, 0, stream>>>(u_W, u_al, u_ar, s_W, s_al, s_ar,
                                                        user_emb, (float4*)elr_u, NU,
                                                        serv_emb, (float4*)elr_s, NS);
    const int nBlocksU = (B + 3) / 4;
    gather_kernel<<<2 * nBlocksU, 256, 0, stream>>>(
        userIdx, indptr_u, csr_u, elr_u, user_emb,
        servIdx, indptr_s, csr_s, elr_s, serv_emb,
        aggbuf, B, nBlocksU);
    const int nPB = (B + PROJ_ROWS - 1) / PROJ_ROWS;
    proj_kernel<<<2 * nPB, 256, 0, stream>>>(
        userIdx, u_W, u_bias, u_ln_g, u_ln_b, user_emb,
        servIdx, s_W, s_bias, s_ln_g, s_ln_b, serv_emb,
        aggbuf, xbuf, B, nPB);
    const int nMB = (B + MLP_ROWS - 1) / MLP_ROWS;
    mlp_kernel<<<nMB, 256, 0, stream>>>(xbuf, ybuf, W1, b1, ln1_g, ln1_b, B);
    mlpfin_kernel<<<nMB, 256, 0, stream>>>(ybuf, (float*)d_out, W2, b2, ln2_g, ln2_b, W3, b3, B);
}